// Round 9
// baseline (305.642 us; speedup 1.0000x reference)
//
#include <hip/hip_runtime.h>

#define BB 16
#define SS 512
#define KIN 512
#define H 256

constexpr float DECAY = 0.951229424500714f;    // exp(-1/20), both tau=20
constexpr float OMD   = 0.048770575499286f;    // 1 - exp(-1/20)
constexpr float LR    = 0.01f;

__device__ __forceinline__ float fast_tanh(float x) {
    float e = __expf(2.f * x);
    return 1.f - __fdividef(2.f, e + 1.f);
}

// Full 64-lane sum via DPP (VALU pipe), broadcast via readlane(63). R2-verified.
__device__ __forceinline__ float wave_sum64(float x) {
    int t;
    t = __builtin_amdgcn_update_dpp(0, __float_as_int(x), 0x111, 0xf, 0xf, false);
    x += __int_as_float(t);
    t = __builtin_amdgcn_update_dpp(0, __float_as_int(x), 0x112, 0xf, 0xf, false);
    x += __int_as_float(t);
    t = __builtin_amdgcn_update_dpp(0, __float_as_int(x), 0x114, 0xf, 0xf, false);
    x += __int_as_float(t);
    t = __builtin_amdgcn_update_dpp(0, __float_as_int(x), 0x118, 0xf, 0xf, false);
    x += __int_as_float(t);
    t = __builtin_amdgcn_update_dpp(0, __float_as_int(x), 0x142, 0xa, 0xf, false);
    x += __int_as_float(t);
    t = __builtin_amdgcn_update_dpp(0, __float_as_int(x), 0x143, 0xc, 0xf, false);
    x += __int_as_float(t);
    return __int_as_float(__builtin_amdgcn_readlane(__float_as_int(x), 63));
}

// i = x @ W^T. ik half (n<256) -> ik_out[b*512+s][256]; iv half -> iv_t[b][row][s].
__global__ __launch_bounds__(256) void gemm_xwT(const float* __restrict__ X,
                                                const float* __restrict__ W,
                                                float* __restrict__ ik_out,
                                                float* __restrict__ iv_t) {
    __shared__ float As[16][68];
    __shared__ float Bs[16][68];
    const int m0 = blockIdx.y * 64;
    const int n0 = blockIdx.x * 64;
    const int tid = threadIdx.x;
    const int r  = tid >> 2;
    const int cg = tid & 3;
    const int tx = tid & 15;
    const int ty = tid >> 4;
    float acc[4][4] = {};
    for (int k0 = 0; k0 < KIN; k0 += 16) {
        float4 av = *(const float4*)&X[(size_t)(m0 + r) * KIN + k0 + cg * 4];
        float4 bv = *(const float4*)&W[(size_t)(n0 + r) * KIN + k0 + cg * 4];
        __syncthreads();
        As[cg*4+0][r] = av.x; As[cg*4+1][r] = av.y; As[cg*4+2][r] = av.z; As[cg*4+3][r] = av.w;
        Bs[cg*4+0][r] = bv.x; Bs[cg*4+1][r] = bv.y; Bs[cg*4+2][r] = bv.z; Bs[cg*4+3][r] = bv.w;
        __syncthreads();
#pragma unroll
        for (int kk = 0; kk < 16; ++kk) {
            float4 a = *(const float4*)&As[kk][ty * 4];
            float4 b = *(const float4*)&Bs[kk][tx * 4];
            float ar[4] = {a.x, a.y, a.z, a.w};
            float br[4] = {b.x, b.y, b.z, b.w};
#pragma unroll
            for (int i = 0; i < 4; ++i)
#pragma unroll
                for (int j = 0; j < 4; ++j) acc[i][j] += ar[i] * br[j];
        }
    }
    if (n0 < 256) {
#pragma unroll
        for (int i = 0; i < 4; ++i) {
            float4 o = make_float4(acc[i][0], acc[i][1], acc[i][2], acc[i][3]);
            *(float4*)&ik_out[(size_t)(m0 + ty * 4 + i) * 256 + n0 + tx * 4] = o;
        }
    } else {
        const int b  = m0 >> 9;
        const int s0 = (m0 & 511) + ty * 4;
#pragma unroll
        for (int j = 0; j < 4; ++j) {
            float4 o = make_float4(acc[0][j], acc[1][j], acc[2][j], acc[3][j]);
            *(float4*)&iv_t[((size_t)b * H + (n0 - 256 + tx * 4 + j)) * SS + s0] = o;
        }
    }
}

// Per (b, col): scan kv, write key only. 32-deep prefetch.
__global__ __launch_bounds__(64) void key_scan(const float* __restrict__ ik,
                                               float* __restrict__ keys) {
    const int idx = blockIdx.x * 64 + threadIdx.x;   // 0..4095
    const int b   = idx >> 8;
    const int col = idx & 255;
    const float* c  = ik + (size_t)b * SS * 256 + col;
    float* ko = keys + (size_t)b * SS * H + col;
    float kv = 0.f;
    constexpr int D = 32;
    float ib[D];
#pragma unroll
    for (int j = 0; j < D; ++j) ib[j] = c[(size_t)j * 256];
    for (int t = 0; t < SS; t += D) {
#pragma unroll
        for (int j = 0; j < D; ++j) {
            float v = ib[j];
            int tn = t + D + j; if (tn > SS - 1) tn = SS - 1;
            ib[j] = c[(size_t)tn * 256];
            kv = DECAY * kv + v;
            ko[(size_t)(t + j) * H] = fast_tanh(kv);
        }
    }
}

// ONE mem-row per 64-lane wave (4 cols/lane) -> 4096 waves = 4 waves/SIMD.
// Keys double-buffered 16 steps in registers (kA/kB, static names); iv 16-step
// double-buffer; vals stores batched 16x (lane j captures step j).
__global__ __launch_bounds__(256, 4) void value_scan(const float* __restrict__ keys,
                                                     const float* __restrict__ iv_t,
                                                     float* __restrict__ mem_out,
                                                     float* __restrict__ vals) {
    const int tid  = threadIdx.x;
    const int wave = tid >> 6;
    const int lane = tid & 63;
    const int b    = blockIdx.x & 15;     // XCD swizzle: batch-mates share an XCD
    const int rg   = blockIdx.x >> 4;     // 0..63
    const int row  = rg * 4 + wave;       // 0..255

    const float* kp  = keys + (size_t)b * SS * H + lane * 4;   // marches +16H
    const float* ivp = iv_t + ((size_t)b * H + row) * SS;      // marches +16
    float* vp = vals + (size_t)b * SS * H + row;               // marches +16H

    float mem[4] = {0.f, 0.f, 0.f, 0.f};
    float ktr[4] = {0.f, 0.f, 0.f, 0.f};
    float vv = 0.f, vt = 0.f, stash = 0.f;

    float4 kA[8], kB[8];
#pragma unroll
    for (int j = 0; j < 8; ++j) kA[j] = *(const float4*)(kp + (size_t)j * H);
#pragma unroll
    for (int j = 0; j < 8; ++j) kB[j] = *(const float4*)(kp + (size_t)(8 + j) * H);
    kp += 16 * H;
    float4 iA0 = *(const float4*)(ivp + 0);
    float4 iA1 = *(const float4*)(ivp + 4);
    float4 iB0 = *(const float4*)(ivp + 8);
    float4 iB1 = *(const float4*)(ivp + 12);
    ivp += 16;

    for (int t2 = 0; t2 < 32; ++t2) {
        const float* kq  = (t2 < 31) ? kp  : (kp - 16 * H);   // clamp (reload dead)
        const float* ivq = (t2 < 31) ? ivp : (ivp - 16);
        float4 nA0 = *(const float4*)(ivq + 0);
        float4 nA1 = *(const float4*)(ivq + 4);
        float4 nB0 = *(const float4*)(ivq + 8);
        float4 nB1 = *(const float4*)(ivq + 12);

        {   // steps t2*16 + 0..7 : consume kA, reload kA for next iter
            float ivs[8] = {iA0.x, iA0.y, iA0.z, iA0.w, iA1.x, iA1.y, iA1.z, iA1.w};
#pragma unroll
            for (int j = 0; j < 8; ++j) {
                float4 kc = kA[j];
                kA[j] = *(const float4*)(kq + (size_t)j * H);
                float p = mem[0] * kc.x + mem[1] * kc.y + mem[2] * kc.z + mem[3] * kc.w;
                float s = wave_sum64(p);
                vv = __builtin_fmaf(DECAY, vv, ivs[j]);
                vv = __builtin_fmaf(0.2f, s, vv);
                float valv = fast_tanh(vv);
                vt = __builtin_fmaf(DECAY, vt, OMD * valv);
                if (lane == j) stash = valv;
                float c = LR * vt;
                float kr[4] = {kc.x, kc.y, kc.z, kc.w};
#pragma unroll
                for (int q = 0; q < 4; ++q) {
                    ktr[q] = __builtin_fmaf(DECAY, ktr[q], OMD * kr[q]);
                    mem[q] = __builtin_fmaf(c * ktr[q], 1.f - mem[q], mem[q]);
                }
            }
        }
        {   // steps t2*16 + 8..15 : consume kB, reload kB for next iter
            float ivs[8] = {iB0.x, iB0.y, iB0.z, iB0.w, iB1.x, iB1.y, iB1.z, iB1.w};
#pragma unroll
            for (int j = 0; j < 8; ++j) {
                float4 kc = kB[j];
                kB[j] = *(const float4*)(kq + (size_t)(8 + j) * H);
                float p = mem[0] * kc.x + mem[1] * kc.y + mem[2] * kc.z + mem[3] * kc.w;
                float s = wave_sum64(p);
                vv = __builtin_fmaf(DECAY, vv, ivs[j]);
                vv = __builtin_fmaf(0.2f, s, vv);
                float valv = fast_tanh(vv);
                vt = __builtin_fmaf(DECAY, vt, OMD * valv);
                if (lane == 8 + j) stash = valv;
                float c = LR * vt;
                float kr[4] = {kc.x, kc.y, kc.z, kc.w};
#pragma unroll
                for (int q = 0; q < 4; ++q) {
                    ktr[q] = __builtin_fmaf(DECAY, ktr[q], OMD * kr[q]);
                    mem[q] = __builtin_fmaf(c * ktr[q], 1.f - mem[q], mem[q]);
                }
            }
        }
        if (lane < 16) vp[(size_t)lane * H] = stash;
        vp += 16 * H;
        kp += 16 * H;
        ivp += 16;
        iA0 = nA0; iA1 = nA1; iB0 = nB0; iB1 = nB1;
    }

    *(float4*)&mem_out[((size_t)b * H + row) * H + lane * 4] =
        make_float4(mem[0], mem[1], mem[2], mem[3]);
}

extern "C" void kernel_launch(void* const* d_in, const int* in_sizes, int n_in,
                              void* d_out, int out_size, void* d_ws, size_t ws_size,
                              hipStream_t stream) {
    const float* x = (const float*)d_in[0];   // [B, S, IN] f32
    const float* W = (const float*)d_in[1];   // [2H, IN] f32
    float* out = (float*)d_out;
    float* mem_out = out;                               // [B, H, H]
    float* keys = out + (size_t)BB * H * H;             // [B, S, H]
    float* vals = keys + (size_t)BB * SS * H;           // [B, S, H]
    float* ik   = (float*)d_ws;                         // [B*S, 256]  8 MB
    float* iv_t = ik + (size_t)BB * SS * 256;           // [B, H, S]   8 MB

    dim3 gb(8, 128);  // N/64, M/64
    gemm_xwT<<<gb, 256, 0, stream>>>(x, W, ik, iv_t);
    key_scan<<<64, 64, 0, stream>>>(ik, keys);
    value_scan<<<1024, 256, 0, stream>>>(keys, iv_t, mem_out, vals);
}

// Round 10
// 266.729 us; speedup vs baseline: 1.1459x; 1.1459x over previous
//
#include <hip/hip_runtime.h>

#define BB 16
#define SS 512
#define KIN 512
#define H 256

typedef float v2f __attribute__((ext_vector_type(2)));

constexpr float DECAY = 0.951229424500714f;    // exp(-1/20), both tau=20
constexpr float OMD   = 0.048770575499286f;    // 1 - exp(-1/20)
constexpr float LR    = 0.01f;

__device__ __forceinline__ float fast_tanh(float x) {
    float e = __expf(2.f * x);
    return 1.f - __fdividef(2.f, e + 1.f);
}

__device__ __forceinline__ v2f pk_mul(v2f a, v2f b) {
    v2f d; asm("v_pk_mul_f32 %0, %1, %2" : "=v"(d) : "v"(a), "v"(b)); return d;
}
__device__ __forceinline__ v2f pk_fma(v2f a, v2f b, v2f c) {
    v2f d; asm("v_pk_fma_f32 %0, %1, %2, %3" : "=v"(d) : "v"(a), "v"(b), "v"(c)); return d;
}

// Per-half all-reduce: 4x DPP row_shr prefix + row_bcast15 (rows 1,3) puts
// sum(0-31) in lane31 and sum(32-63) in lane63; ds_swizzle 0x3E0 (src lane31
// of each 32-group) broadcasts each half's own sum to all its lanes.
__device__ __forceinline__ float allred32(float x) {
    int t;
    t = __builtin_amdgcn_update_dpp(0, __float_as_int(x), 0x111, 0xf, 0xf, false);
    x += __int_as_float(t);
    t = __builtin_amdgcn_update_dpp(0, __float_as_int(x), 0x112, 0xf, 0xf, false);
    x += __int_as_float(t);
    t = __builtin_amdgcn_update_dpp(0, __float_as_int(x), 0x114, 0xf, 0xf, false);
    x += __int_as_float(t);
    t = __builtin_amdgcn_update_dpp(0, __float_as_int(x), 0x118, 0xf, 0xf, false);
    x += __int_as_float(t);
    t = __builtin_amdgcn_update_dpp(0, __float_as_int(x), 0x142, 0xa, 0xf, false);
    x += __int_as_float(t);
    return __int_as_float(__builtin_amdgcn_ds_swizzle(__float_as_int(x), 0x3E0));
}

// i = x @ W^T. ik half (n<256) -> ik_out[b*512+s][256]; iv half -> iv_t[b][row][s].
__global__ __launch_bounds__(256) void gemm_xwT(const float* __restrict__ X,
                                                const float* __restrict__ W,
                                                float* __restrict__ ik_out,
                                                float* __restrict__ iv_t) {
    __shared__ float As[16][68];
    __shared__ float Bs[16][68];
    const int m0 = blockIdx.y * 64;
    const int n0 = blockIdx.x * 64;
    const int tid = threadIdx.x;
    const int r  = tid >> 2;
    const int cg = tid & 3;
    const int tx = tid & 15;
    const int ty = tid >> 4;
    float acc[4][4] = {};
    for (int k0 = 0; k0 < KIN; k0 += 16) {
        float4 av = *(const float4*)&X[(size_t)(m0 + r) * KIN + k0 + cg * 4];
        float4 bv = *(const float4*)&W[(size_t)(n0 + r) * KIN + k0 + cg * 4];
        __syncthreads();
        As[cg*4+0][r] = av.x; As[cg*4+1][r] = av.y; As[cg*4+2][r] = av.z; As[cg*4+3][r] = av.w;
        Bs[cg*4+0][r] = bv.x; Bs[cg*4+1][r] = bv.y; Bs[cg*4+2][r] = bv.z; Bs[cg*4+3][r] = bv.w;
        __syncthreads();
#pragma unroll
        for (int kk = 0; kk < 16; ++kk) {
            float4 a = *(const float4*)&As[kk][ty * 4];
            float4 b = *(const float4*)&Bs[kk][tx * 4];
            float ar[4] = {a.x, a.y, a.z, a.w};
            float br[4] = {b.x, b.y, b.z, b.w};
#pragma unroll
            for (int i = 0; i < 4; ++i)
#pragma unroll
                for (int j = 0; j < 4; ++j) acc[i][j] += ar[i] * br[j];
        }
    }
    if (n0 < 256) {
#pragma unroll
        for (int i = 0; i < 4; ++i) {
            float4 o = make_float4(acc[i][0], acc[i][1], acc[i][2], acc[i][3]);
            *(float4*)&ik_out[(size_t)(m0 + ty * 4 + i) * 256 + n0 + tx * 4] = o;
        }
    } else {
        const int b  = m0 >> 9;
        const int s0 = (m0 & 511) + ty * 4;
#pragma unroll
        for (int j = 0; j < 4; ++j) {
            float4 o = make_float4(acc[0][j], acc[1][j], acc[2][j], acc[3][j]);
            *(float4*)&iv_t[((size_t)b * H + (n0 - 256 + tx * 4 + j)) * SS + s0] = o;
        }
    }
}

// Per (b, col): scan kv; write key to output and kt in-place over ik.
__global__ __launch_bounds__(64) void key_scan(float* ik,
                                               float* __restrict__ keys) {
    const int idx = blockIdx.x * 64 + threadIdx.x;   // 0..4095
    const int b   = idx >> 8;
    const int col = idx & 255;
    float* c  = ik + (size_t)b * SS * 256 + col;
    float* ko = keys + (size_t)b * SS * H + col;
    float kv = 0.f, kt = 0.f;
    constexpr int D = 32;
    float ib[D];
#pragma unroll
    for (int j = 0; j < D; ++j) ib[j] = c[(size_t)j * 256];
    for (int t = 0; t < SS; t += D) {
#pragma unroll
        for (int j = 0; j < D; ++j) {
            float v = ib[j];
            int tn = t + D + j; if (tn > SS - 1) tn = SS - 1;
            ib[j] = c[(size_t)tn * 256];
            kv = DECAY * kv + v;
            float key = fast_tanh(kv);
            kt = __builtin_fmaf(DECAY, kt, OMD * key);
            ko[(size_t)(t + j) * H] = key;
            c[(size_t)(t + j) * 256] = kt;
        }
    }
}

// 2 mem-rows per wave (32 lanes/row, 8 cols/lane). kt loaded (precomputed),
// 8-step register ring for keys+kt pinned by per-step asm memory barriers,
// swizzle-broadcast reduce (no readlane/select), vals stores batched 16x.
__global__ __launch_bounds__(256, 2) void value_scan(const float* __restrict__ keys,
                                                     const float* __restrict__ kts,
                                                     const float* __restrict__ iv_t,
                                                     float* __restrict__ mem_out,
                                                     float* __restrict__ vals) {
    const int tid  = threadIdx.x;
    const int wave = tid >> 6;
    const int lane = tid & 63;
    const int half = lane >> 5;
    const int sub  = lane & 31;
    const int b    = blockIdx.x & 15;     // XCD swizzle: batch-mates share an XCD
    const int rg   = blockIdx.x >> 4;
    const int row  = rg * 8 + wave * 2 + half;
    const int so   = sub * 8;

    const float* kp  = keys + (size_t)b * SS * H + so;
    const float* tp  = kts  + (size_t)b * SS * H + so;
    const float* ivp = iv_t + ((size_t)b * H + row) * SS;
    float* vrow = vals + (size_t)b * SS * H + row;

    const v2f ONE2 = {1.f, 1.f};
    const v2f NM12 = {-1.f, -1.f};

    v2f mem2[4] = {{0.f,0.f},{0.f,0.f},{0.f,0.f},{0.f,0.f}};
    float vv = 0.f, vt = 0.f, stash = 0.f;

    // 8-step ring: keys + kt, 4 v2f each (8 cols/lane)
    v2f kR[8][4], tR[8][4];
#pragma unroll
    for (int j = 0; j < 8; ++j)
#pragma unroll
        for (int q = 0; q < 4; ++q) {
            kR[j][q] = *(const v2f*)(kp + (size_t)j * H + q * 2);
            tR[j][q] = *(const v2f*)(tp + (size_t)j * H + q * 2);
        }
    const float* kpF = kp + 8 * H;
    const float* tpF = tp + 8 * H;

    float4 iA0 = *(const float4*)(ivp + 0);
    float4 iA1 = *(const float4*)(ivp + 4);
    float4 iB0 = *(const float4*)(ivp + 8);
    float4 iB1 = *(const float4*)(ivp + 12);
    ivp += 16;

#define VS_STEP(J, RELOAD)                                                     \
    {                                                                          \
        v2f kc0 = kR[(J)&7][0], kc1 = kR[(J)&7][1],                            \
            kc2 = kR[(J)&7][2], kc3 = kR[(J)&7][3];                            \
        v2f tc0 = tR[(J)&7][0], tc1 = tR[(J)&7][1],                            \
            tc2 = tR[(J)&7][2], tc3 = tR[(J)&7][3];                            \
        if (RELOAD) {                                                          \
            kR[(J)&7][0] = *(const v2f*)(kpF + ((J)&3) * H + 0);               \
            kR[(J)&7][1] = *(const v2f*)(kpF + ((J)&3) * H + 2);               \
            kR[(J)&7][2] = *(const v2f*)(kpF + ((J)&3) * H + 4);               \
            kR[(J)&7][3] = *(const v2f*)(kpF + ((J)&3) * H + 6);               \
            tR[(J)&7][0] = *(const v2f*)(tpF + ((J)&3) * H + 0);               \
            tR[(J)&7][1] = *(const v2f*)(tpF + ((J)&3) * H + 2);               \
            tR[(J)&7][2] = *(const v2f*)(tpF + ((J)&3) * H + 4);               \
            tR[(J)&7][3] = *(const v2f*)(tpF + ((J)&3) * H + 6);               \
        }                                                                      \
        v2f p2 = pk_mul(mem2[0], kc0);                                         \
        p2 = pk_fma(mem2[1], kc1, p2);                                         \
        p2 = pk_fma(mem2[2], kc2, p2);                                         \
        p2 = pk_fma(mem2[3], kc3, p2);                                         \
        float s = allred32(p2.x + p2.y);                                       \
        vv = __builtin_fmaf(DECAY, vv, ivs[J]);                                \
        vv = __builtin_fmaf(0.2f, s, vv);                                      \
        float valv = fast_tanh(vv);                                            \
        vt = __builtin_fmaf(DECAY, vt, OMD * valv);                            \
        if (sub == (J)) stash = valv;                                          \
        float c = LR * vt;                                                     \
        v2f c2 = {c, c};                                                       \
        v2f d0 = pk_fma(mem2[0], NM12, ONE2);                                  \
        v2f d1 = pk_fma(mem2[1], NM12, ONE2);                                  \
        v2f d2 = pk_fma(mem2[2], NM12, ONE2);                                  \
        v2f d3 = pk_fma(mem2[3], NM12, ONE2);                                  \
        mem2[0] = pk_fma(pk_mul(c2, tc0), d0, mem2[0]);                        \
        mem2[1] = pk_fma(pk_mul(c2, tc1), d1, mem2[1]);                        \
        mem2[2] = pk_fma(pk_mul(c2, tc2), d2, mem2[2]);                        \
        mem2[3] = pk_fma(pk_mul(c2, tc3), d3, mem2[3]);                        \
        asm volatile("" ::: "memory");                                         \
    }

    for (int t0 = 0; t0 < SS - 16; t0 += 16) {
        float4 nA0 = *(const float4*)(ivp + 0);
        float4 nA1 = *(const float4*)(ivp + 4);
        float4 nB0 = *(const float4*)(ivp + 8);
        float4 nB1 = *(const float4*)(ivp + 12);
        ivp += 16;
        {
            float ivs[16] = {iA0.x, iA0.y, iA0.z, iA0.w,
                             iA1.x, iA1.y, iA1.z, iA1.w,
                             iB0.x, iB0.y, iB0.z, iB0.w,
                             iB1.x, iB1.y, iB1.z, iB1.w};
            VS_STEP(0, 1)  VS_STEP(1, 1)  VS_STEP(2, 1)  VS_STEP(3, 1)
            kpF += 4 * H; tpF += 4 * H;
            VS_STEP(4, 1)  VS_STEP(5, 1)  VS_STEP(6, 1)  VS_STEP(7, 1)
            kpF += 4 * H; tpF += 4 * H;
            VS_STEP(8, 1)  VS_STEP(9, 1)  VS_STEP(10, 1) VS_STEP(11, 1)
            kpF += 4 * H; tpF += 4 * H;
            VS_STEP(12, 1) VS_STEP(13, 1) VS_STEP(14, 1) VS_STEP(15, 1)
            kpF += 4 * H; tpF += 4 * H;
        }
        if (sub < 16) vrow[(size_t)sub * H] = stash;
        vrow += 16 * H;
        iA0 = nA0; iA1 = nA1; iB0 = nB0; iB1 = nB1;
    }
    {   // final tile: steps 496-503 fetch 504-511; steps 504-511 no reload
        float ivs[16] = {iA0.x, iA0.y, iA0.z, iA0.w,
                         iA1.x, iA1.y, iA1.z, iA1.w,
                         iB0.x, iB0.y, iB0.z, iB0.w,
                         iB1.x, iB1.y, iB1.z, iB1.w};
        VS_STEP(0, 1)  VS_STEP(1, 1)  VS_STEP(2, 1)  VS_STEP(3, 1)
        kpF += 4 * H; tpF += 4 * H;
        VS_STEP(4, 1)  VS_STEP(5, 1)  VS_STEP(6, 1)  VS_STEP(7, 1)
        VS_STEP(8, 0)  VS_STEP(9, 0)  VS_STEP(10, 0) VS_STEP(11, 0)
        VS_STEP(12, 0) VS_STEP(13, 0) VS_STEP(14, 0) VS_STEP(15, 0)
        if (sub < 16) vrow[(size_t)sub * H] = stash;
    }
#undef VS_STEP

    float* mo = &mem_out[((size_t)b * H + row) * H + so];
    *(float4*)&mo[0] = make_float4(mem2[0].x, mem2[0].y, mem2[1].x, mem2[1].y);
    *(float4*)&mo[4] = make_float4(mem2[2].x, mem2[2].y, mem2[3].x, mem2[3].y);
}

extern "C" void kernel_launch(void* const* d_in, const int* in_sizes, int n_in,
                              void* d_out, int out_size, void* d_ws, size_t ws_size,
                              hipStream_t stream) {
    const float* x = (const float*)d_in[0];   // [B, S, IN] f32
    const float* W = (const float*)d_in[1];   // [2H, IN] f32
    float* out = (float*)d_out;
    float* mem_out = out;                               // [B, H, H]
    float* keys = out + (size_t)BB * H * H;             // [B, S, H]
    float* vals = keys + (size_t)BB * SS * H;           // [B, S, H]
    float* ik   = (float*)d_ws;                         // [B*S, 256]  8 MB (becomes kt)
    float* iv_t = ik + (size_t)BB * SS * 256;           // [B, H, S]   8 MB

    dim3 gb(8, 128);  // N/64, M/64
    gemm_xwT<<<gb, 256, 0, stream>>>(x, W, ik, iv_t);
    key_scan<<<64, 64, 0, stream>>>(ik, keys);
    value_scan<<<512, 256, 0, stream>>>(keys, ik, iv_t, mem_out, vals);
}